// Round 6
// baseline (211.737 us; speedup 1.0000x reference)
//
#include <hip/hip_runtime.h>
#include <hip/hip_bf16.h>

typedef __hip_bfloat16 bf16;
typedef __attribute__((ext_vector_type(8))) short short8;
typedef __attribute__((ext_vector_type(4))) float f32x4;

#define DEV static __device__ __forceinline__

static constexpr int SEQ = 2048;
static constexpr int DM  = 1024;
static constexpr int NH  = 16;
static constexpr int HD  = 64;
static constexpr int WIN = 2048;
static constexpr int PAD = 1024;   // WIN/2

// async global->LDS, 16B per lane; LDS dest = wave-uniform base + lane*16
DEV void async16(const void* g, void* l) {
  __builtin_amdgcn_global_load_lds(
      (__attribute__((address_space(1))) void*)(g),
      (__attribute__((address_space(3))) void*)(l), 16, 0, 0);
}

// ---------------------------------------------------------------- K0: f32 -> bf16 convert (x, w_qkv, w_proj)
__global__ __launch_bounds__(256) void k_cvt(const float* __restrict__ x,
                                             const float* __restrict__ wq,
                                             const float* __restrict__ wp,
                                             bf16* __restrict__ xb,
                                             bf16* __restrict__ wqb,
                                             bf16* __restrict__ wpb) {
  const int NX = SEQ * DM, NQ = 3 * DM * DM, NP = DM * DM;
  const int tot = (NX + NQ + NP) >> 2;
  const int stride = gridDim.x * 256;
  for (int i = blockIdx.x * 256 + threadIdx.x; i < tot; i += stride) {
    int e = i << 2;
    const float* s; bf16* d; int o;
    if (e < NX)            { s = x;  d = xb;  o = e; }
    else if (e < NX + NQ)  { s = wq; d = wqb; o = e - NX; }
    else                   { s = wp; d = wpb; o = e - NX - NQ; }
    float4 v = *(const float4*)(s + o);
    __align__(8) bf16 t4[4] = {__float2bfloat16(v.x), __float2bfloat16(v.y),
                               __float2bfloat16(v.z), __float2bfloat16(v.w)};
    *(uint2*)(d + o) = *(uint2*)t4;
  }
}

// ---------------------------------------------------------------- shared GEMM core: C[m][n] = sum_k A[m][k]*B[n][k]
DEV void gemm_core(const bf16* __restrict__ A, const bf16* __restrict__ B,
                   int m0, int n0, int K, int tid, bf16* As, bf16* Bs,
                   f32x4 (&acc)[4][4]) {
  const int lane = tid & 63, wid = tid >> 6;
  const int wm = wid >> 1, wn = wid & 1;
  const int l15 = lane & 15, l4 = lane >> 4;
  for (int k0 = 0; k0 < K; k0 += 64) {
    __syncthreads();
    #pragma unroll
    for (int it = 0; it < 4; ++it) {
      int rb = it * 32 + wid * 8;
      int r  = rb + (lane >> 3);
      int c  = (lane & 7) * 8;
      async16(A + (size_t)(m0 + r) * K + k0 + c, As + rb * 64);
      async16(B + (size_t)(n0 + r) * K + k0 + c, Bs + rb * 64);
    }
    asm volatile("s_waitcnt vmcnt(0)" ::: "memory");
    __syncthreads();
    #pragma unroll
    for (int kk = 0; kk < 2; ++kk) {
      short8 a[4], b[4];
      #pragma unroll
      for (int im = 0; im < 4; ++im)
        a[im] = *(const short8*)(As + (wm * 64 + im * 16 + l15) * 64 + kk * 32 + l4 * 8);
      #pragma unroll
      for (int in = 0; in < 4; ++in)
        b[in] = *(const short8*)(Bs + (wn * 64 + in * 16 + l15) * 64 + kk * 32 + l4 * 8);
      #pragma unroll
      for (int im = 0; im < 4; ++im)
        #pragma unroll
        for (int in = 0; in < 4; ++in)
          acc[im][in] = __builtin_amdgcn_mfma_f32_16x16x32_bf16(a[im], b[in], acc[im][in], 0, 0, 0);
    }
  }
}

// ---------------------------------------------------------------- K1: qkv GEMM + scatter to per-head q(scaled)/k/v
__global__ __launch_bounds__(256) void k_gemm_qkv(const bf16* __restrict__ A,
                                                  const bf16* __restrict__ B,
                                                  const float* __restrict__ bias,
                                                  bf16* __restrict__ qo,
                                                  bf16* __restrict__ ko,
                                                  bf16* __restrict__ vo) {
  __shared__ bf16 As[128 * 64], Bs[128 * 64];
  const int tid = threadIdx.x, lane = tid & 63;
  const int wid = tid >> 6, wm = wid >> 1, wn = wid & 1;
  const int l15 = lane & 15, l4 = lane >> 4;
  const int m0 = blockIdx.x * 128, n0 = blockIdx.y * 128;
  f32x4 acc[4][4] = {};
  gemm_core(A, B, m0, n0, DM, tid, As, Bs, acc);
  #pragma unroll
  for (int im = 0; im < 4; ++im)
    #pragma unroll
    for (int in = 0; in < 4; ++in) {
      int col = n0 + wn * 64 + in * 16 + l15;
      float bval = bias[col];
      int t = col >> 10, h = (col >> 6) & 15, dd = col & 63;
      #pragma unroll
      for (int r = 0; r < 4; ++r) {
        int row = m0 + wm * 64 + im * 16 + l4 * 4 + r;
        float v = acc[im][in][r] + bval;
        size_t idx = ((size_t)h * SEQ + row) * HD + dd;
        // q folded with hd^-0.5 * log2(e) so scores feed exp2 directly
        if (t == 0)      qo[idx] = __float2bfloat16(v * 0.18033688011112042f);
        else if (t == 1) ko[idx] = __float2bfloat16(v);
        else             vo[idx] = __float2bfloat16(v);
      }
    }
}

// ---------------------------------------------------------------- K1b: transpose v [h][j][d] -> vT [h][d][j]
__global__ __launch_bounds__(256) void k_vt(const bf16* __restrict__ v, bf16* __restrict__ vT) {
  const int h = blockIdx.x >> 5;
  const int j0 = (blockIdx.x & 31) * 64;
  __shared__ bf16 t[64 * 64];
  const int tid = threadIdx.x;
  #pragma unroll
  for (int it = 0; it < 2; ++it) {
    int c = it * 256 + tid;
    int r = c >> 3, cg = c & 7;
    short8 val = *(const short8*)&v[((size_t)h * SEQ + j0 + r) * HD + cg * 8];
    int pg = cg ^ ((r >> 3) & 7);
    *(short8*)&t[r * 64 + pg * 8] = val;
  }
  __syncthreads();
  #pragma unroll
  for (int it = 0; it < 2; ++it) {
    int c = it * 256 + tid;
    int dd = c >> 3, jj0 = (c & 7) * 8;
    union { unsigned short u[8]; short8 v8; } o;
    #pragma unroll
    for (int e = 0; e < 8; ++e) {
      int j = jj0 + e;
      int pg = (dd >> 3) ^ ((j >> 3) & 7);
      o.u[e] = *(unsigned short*)&t[j * 64 + pg * 8 + (dd & 7)];
    }
    *(short8*)&vT[((size_t)h * HD + dd) * SEQ + j0 + jj0] = o.v8;
  }
}

// ---------------------------------------------------------------- K1c: zero aof accumulator
__global__ __launch_bounds__(256) void k_zero(float* __restrict__ p) {
  int i = blockIdx.x * 256 + threadIdx.x;
  ((float4*)p)[i] = float4{0.f, 0.f, 0.f, 0.f};
}

// ---------------------------------------------------------------- attn helpers
// Direct-from-global K fragments (karr is 4 MB -> L2-resident; reuse/block = 1,
// so LDS staging is pure overhead — Common-mistake #7).
DEV void load_kf(const bf16* kbase, int i0, int tt, int l15, int l4,
                 short8 (&kf)[2][2]) {
  #pragma unroll
  for (int fn = 0; fn < 2; ++fn) {
    int jp = i0 + tt * 32 + fn * 16 + l15;     // absolute j'
    int krow = jp - PAD;                       // clamp; pad handled analytically
    krow = krow < 0 ? 0 : (krow > SEQ - 1 ? SEQ - 1 : krow);
    const bf16* rp = kbase + (size_t)krow * HD + l4 * 8;
    kf[fn][0] = *(const short8*)(rp);
    kf[fn][1] = *(const short8*)(rp + 32);
  }
}

// unswapped: A = Q rows i, B = K rows j'  ->  sf[fm][fn]: col=j'(l15), row=i(l4*4+r)
DEV void qk_mfma(const short8 (&kf)[2][2], const short8 (&qf)[2][2],
                 f32x4 (&sf)[2][2]) {
  #pragma unroll
  for (int kg = 0; kg < 2; ++kg)
    #pragma unroll
    for (int fm = 0; fm < 2; ++fm)
      #pragma unroll
      for (int fn = 0; fn < 2; ++fn)
        sf[fm][fn] = __builtin_amdgcn_mfma_f32_16x16x32_bf16(qf[fm][kg], kf[fn][kg], sf[fm][fn], 0, 0, 0);
}

// swapped QK (attn1 only): sf[fj][fi]: col=i(l15), row=j'(l4*4+r)
DEV void qk_mfma_sw(const short8 (&kf)[2][2], const short8 (&qf)[2][2],
                    f32x4 (&sf)[2][2]) {
  #pragma unroll
  for (int kg = 0; kg < 2; ++kg)
    #pragma unroll
    for (int fj = 0; fj < 2; ++fj)
      #pragma unroll
      for (int fi = 0; fi < 2; ++fi)
        sf[fj][fi] = __builtin_amdgcn_mfma_f32_16x16x32_bf16(kf[fj][kg], qf[fi][kg], sf[fj][fi], 0, 0, 0);
}

DEV int pad_lo(int i0) { int d = PAD - i0; return d <= 0 ? 0 : (d >> 5); }
DEV int pad_hi(int i0) { int t = ((PAD + SEQ - 1 - i0) >> 5) + 1; return t > 65 ? 65 : t; }

// ---------------------------------------------------------------- K2a: partial exp-sums per window chunk
__global__ __launch_bounds__(64) void k_attn1(const bf16* __restrict__ q,
                                              const bf16* __restrict__ kkk,
                                              float* __restrict__ psums) {
  const int c  = blockIdx.x & 3;
  const int i0 = ((blockIdx.x >> 2) & 63) << 5;
  const int h  = blockIdx.x >> 8;
  const int lane = threadIdx.x;
  const int l15 = lane & 15, l4 = lane >> 4;
  constexpr int st[5] = {0, 16, 32, 48, 65};
  const int lo_g = pad_lo(i0), hi_g = pad_hi(i0);
  int lo = st[c] > lo_g ? st[c] : lo_g;
  int hi = st[c + 1] < hi_g ? st[c + 1] : hi_g;

  short8 qf[2][2];
  #pragma unroll
  for (int fi = 0; fi < 2; ++fi)
    #pragma unroll
    for (int kg = 0; kg < 2; ++kg)
      qf[fi][kg] = *(const short8*)&q[((size_t)h * SEQ + i0 + fi * 16 + l15) * HD + kg * 32 + l4 * 8];

  const bf16* kbase = kkk + (size_t)h * SEQ * HD;

  float psum[2] = {0.f, 0.f};
  for (int tt = lo; tt < hi; ++tt) {
    short8 kf[2][2];
    load_kf(kbase, i0, tt, l15, l4, kf);
    f32x4 sf[2][2] = {};
    qk_mfma_sw(kf, qf, sf);
    const bool interior = (tt >= 1) && (tt <= 63) &&
                          (i0 + tt * 32 >= PAD) && (i0 + tt * 32 + 31 < PAD + SEQ);
    if (interior) {
      #pragma unroll
      for (int fj = 0; fj < 2; ++fj)
        #pragma unroll
        for (int r = 0; r < 4; ++r) {
          psum[0] += __builtin_amdgcn_exp2f(sf[fj][0][r]);
          psum[1] += __builtin_amdgcn_exp2f(sf[fj][1][r]);
        }
    } else {
      #pragma unroll
      for (int fj = 0; fj < 2; ++fj)
        #pragma unroll
        for (int r = 0; r < 4; ++r) {
          int jj = tt * 32 + fj * 16 + l4 * 4 + r;   // local j'
          int jp = i0 + jj;                          // absolute j'
          bool pad = (jp < PAD) || (jp >= PAD + SEQ);
          #pragma unroll
          for (int fi = 0; fi < 2; ++fi) {
            int iloc = fi * 16 + l15;
            float e = pad ? 1.0f : __builtin_amdgcn_exp2f(sf[fj][fi][r]);
            if ((unsigned)(jj - iloc) < (unsigned)WIN) psum[fi] += e;
          }
        }
    }
  }
  float r0 = psum[0];
  r0 += __shfl_xor(r0, 16); r0 += __shfl_xor(r0, 32);
  float r1 = psum[1];
  r1 += __shfl_xor(r1, 16); r1 += __shfl_xor(r1, 32);
  if (lane < 32) {
    int i_abs = i0 + lane;
    float s = (lane < 16) ? r0 : r1;
    if (c == 0) {
      int cl = i0 + lo_g * 32 - i_abs; if (cl < 0) cl = 0;
      int cr = i_abs + WIN - (i0 + hi_g * 32); if (cr < 0) cr = 0;
      s += (float)(cl + cr);                  // analytic all-pad contribution
    }
    psums[((size_t)c * NH + h) * SEQ + i_abs] = s;
  }
}

// ---------------------------------------------------------------- K2b: recompute + normalize + ALIGNED attn flush + PV
// Diagonal tiles are re-binned into a j-aligned f32 LDS ring (JF); completed
// 32-wide j-tiles are flushed as full-128B-line nontemporal dwordx4 stores.
__global__ __launch_bounds__(64) void k_attn2(const bf16* __restrict__ q,
                                              const bf16* __restrict__ kkk,
                                              const bf16* __restrict__ vT,
                                              const float* __restrict__ psums,
                                              float* __restrict__ attn,
                                              float* __restrict__ aof) {
  const int c  = blockIdx.x & 3;
  const int i0 = ((blockIdx.x >> 2) & 63) << 5;
  const int h  = blockIdx.x >> 8;
  const int lane = threadIdx.x;
  const int l15 = lane & 15, l4 = lane >> 4;
  const int c0 = c * 16, c1 = c0 + 16;
  const int lo_g = pad_lo(i0), hi_g = pad_hi(i0);

  __shared__ float JF[32 * 64];    // j-aligned f32 ring; 4-float groups XOR-swizzled by row

  // inverse row sums (row = i0 + fm*16 + l4*4 + r)
  float inv[2][4];
  #pragma unroll
  for (int fm = 0; fm < 2; ++fm)
    #pragma unroll
    for (int r = 0; r < 4; ++r) {
      int row = i0 + fm * 16 + l4 * 4 + r;
      float s = 0.f;
      #pragma unroll
      for (int cc = 0; cc < 4; ++cc)
        s += psums[((size_t)cc * NH + h) * SEQ + row];
      inv[fm][r] = __builtin_amdgcn_rcpf(s);
    }

  short8 qf[2][2];
  #pragma unroll
  for (int fm = 0; fm < 2; ++fm)
    #pragma unroll
    for (int kg = 0; kg < 2; ++kg)
      qf[fm][kg] = *(const short8*)&q[((size_t)h * SEQ + i0 + fm * 16 + l15) * HD + kg * 32 + l4 * 8];

  const bf16* kbase = kkk + (size_t)h * SEQ * HD;
  const bf16* vbase = vT + (size_t)h * HD * SEQ;
  float* abase = attn + (size_t)(h * SEQ + i0) * WIN;

  f32x4 oacc[2][4] = {};
  for (int tt = c0; tt <= c1; ++tt) {
    // PV B-fragments (vT, L2-resident)
    short8 bv[4];
    if (tt > c0) {
      int jb = (tt - 1) * 32;
      #pragma unroll
      for (int nd = 0; nd < 4; ++nd)
        bv[nd] = *(const short8*)&vbase[(size_t)(nd * 16 + l15) * SEQ + jb + l4 * 8];
    }

    const bool fp = (tt < lo_g) || (tt >= hi_g);   // all-pad tile: score==0
    f32x4 sf[2][2] = {};
    if (!fp) {
      short8 kf[2][2];
      load_kf(kbase, i0, tt, l15, l4, kf);
      qk_mfma(kf, qf, sf);
    }

    // re-bin diagonal tile into j-aligned JF ring
    const bool allv = (i0 + tt * 32 >= PAD) && (i0 + tt * 32 + 31 < PAD + SEQ);
    #pragma unroll
    for (int fm = 0; fm < 2; ++fm)
      #pragma unroll
      for (int fn = 0; fn < 2; ++fn) {
        int J0 = tt * 32 + fn * 16 + l15;          // local j' (col)
        bool padc = fp || (!allv && ((i0 + J0 < PAD) || (i0 + J0 >= PAD + SEQ)));
        #pragma unroll
        for (int r = 0; r < 4; ++r) {
          int row = fm * 16 + l4 * 4 + r;          // local i
          float e = padc ? 1.0f : __builtin_amdgcn_exp2f(sf[fm][fn][r]);
          float val = e * inv[fm][r];
          int j6 = (J0 - row) & 63;                // ring position
          int pgrp = (j6 >> 2) ^ ((row & 7) << 1);
          JF[row * 64 + pgrp * 4 + (j6 & 3)] = val;
        }
      }

    if (tt > c0) {
      const int g = (tt - 1) & 1;                  // ring slot of completed j-tile
      const int Jb = (tt - 1) * 32;
      // flush: 4 instrs, each 8 rows x full 128B line, nontemporal
      #pragma unroll
      for (int s = 0; s < 4; ++s) {
        int row = s * 8 + (lane >> 3);
        int c8 = lane & 7;
        int pgrp = (g * 8 + c8) ^ ((row & 7) << 1);
        f32x4 vv = *(const f32x4*)&JF[row * 64 + pgrp * 4];
        __builtin_nontemporal_store(vv, (f32x4*)(abase + (size_t)row * WIN + Jb + c8 * 4));
      }
      // PV A-fragments from JF (f32 -> bf16)
      short8 af[2];
      #pragma unroll
      for (int fm = 0; fm < 2; ++fm) {
        int row = fm * 16 + l15;
        int pg0 = (g * 8 + l4 * 2) ^ ((row & 7) << 1);   // even; +1 adjacent
        const float* p = &JF[row * 64 + pg0 * 4];
        union { unsigned short u[8]; short8 v; } tmp;
        #pragma unroll
        for (int e = 0; e < 8; ++e)
          tmp.u[e] = __bfloat16_as_ushort(__float2bfloat16(p[e]));
        af[fm] = tmp.v;
      }
      #pragma unroll
      for (int fm = 0; fm < 2; ++fm)
        #pragma unroll
        for (int nd = 0; nd < 4; ++nd)
          oacc[fm][nd] = __builtin_amdgcn_mfma_f32_16x16x32_bf16(af[fm], bv[nd], oacc[fm][nd], 0, 0, 0);
    }
  }
  // accumulate partial O (cross-chunk reduction)
  #pragma unroll
  for (int fm = 0; fm < 2; ++fm)
    #pragma unroll
    for (int nd = 0; nd < 4; ++nd)
      #pragma unroll
      for (int r = 0; r < 4; ++r) {
        int i  = i0 + fm * 16 + l4 * 4 + r;
        int dd = nd * 16 + l15;
        atomicAdd(&aof[((size_t)h * SEQ + i) * HD + dd], oacc[fm][nd][r]);
      }
}

// ---------------------------------------------------------------- K2c: aof f32 [h][i][dd] -> ao bf16 [i][h*64+dd]
__global__ __launch_bounds__(256) void k_ored(const float* __restrict__ aof,
                                              bf16* __restrict__ ao) {
  int f = blockIdx.x * 256 + threadIdx.x;
  int e = f << 2;
  int h  = e >> 17;
  int i  = (e >> 6) & (SEQ - 1);
  int dd = e & 63;
  float4 v = ((const float4*)aof)[f];
  __align__(8) bf16 t4[4] = {__float2bfloat16(v.x), __float2bfloat16(v.y),
                             __float2bfloat16(v.z), __float2bfloat16(v.w)};
  *(uint2*)&ao[(size_t)i * DM + h * HD + dd] = *(uint2*)t4;
}

// ---------------------------------------------------------------- K4: proj GEMM -> d_out (f32)
__global__ __launch_bounds__(256) void k_gemm_proj(const bf16* __restrict__ A,
                                                   const bf16* __restrict__ B,
                                                   const float* __restrict__ bias,
                                                   float* __restrict__ out) {
  __shared__ bf16 As[128 * 64], Bs[128 * 64];
  const int tid = threadIdx.x, lane = tid & 63;
  const int wid = tid >> 6, wm = wid >> 1, wn = wid & 1;
  const int l15 = lane & 15, l4 = lane >> 4;
  const int m0 = blockIdx.x * 128, n0 = blockIdx.y * 128;
  f32x4 acc[4][4] = {};
  gemm_core(A, B, m0, n0, DM, tid, As, Bs, acc);
  #pragma unroll
  for (int im = 0; im < 4; ++im)
    #pragma unroll
    for (int in = 0; in < 4; ++in) {
      int col = n0 + wn * 64 + in * 16 + l15;
      float bval = bias[col];
      #pragma unroll
      for (int r = 0; r < 4; ++r) {
        int row = m0 + wm * 64 + im * 16 + l4 * 4 + r;
        out[(size_t)row * DM + col] = acc[im][in][r] + bval;
      }
    }
}

// ---------------------------------------------------------------- launch
extern "C" void kernel_launch(void* const* d_in, const int* in_sizes, int n_in,
                              void* d_out, int out_size, void* d_ws, size_t ws_size,
                              hipStream_t stream) {
  (void)in_sizes; (void)n_in; (void)out_size; (void)ws_size;
  const float* x  = (const float*)d_in[0];
  const float* wq = (const float*)d_in[1];
  const float* bq = (const float*)d_in[2];
  const float* wp = (const float*)d_in[3];
  const float* bp = (const float*)d_in[4];
  float* out  = (float*)d_out;
  float* attn = out + (size_t)SEQ * DM;

  char* ws = (char*)d_ws;
  bf16* xb    = (bf16*)(ws + (size_t) 0);          // 4 MB  x bf16            [dead after qkv gemm]
  bf16* wqb   = (bf16*)(ws + ((size_t)4  << 20));  // 6 MB  w_qkv bf16        [dead after qkv gemm]
  bf16* wpb   = (bf16*)(ws + ((size_t)10 << 20));  // 2 MB  w_proj bf16
  bf16* qarr  = (bf16*)(ws + ((size_t)12 << 20));  // 4 MB  q [h][i][d] (scale*log2e folded)
  bf16* karr  = (bf16*)(ws + ((size_t)16 << 20));  // 4 MB  k [h][j][d]
  bf16* varr  = (bf16*)(ws + ((size_t)20 << 20));  // 4 MB  v [h][j][d]
  bf16* vt    = (bf16*)(ws + ((size_t)24 << 20));  // 4 MB  vT [h][d][j]
  bf16* ao    = (bf16*)(ws + ((size_t)28 << 20));  // 4 MB  attn-out rows [i][h*64+d]
  float* aof  = (float*)(ws + (size_t)0);          // 8 MB  f32 O accum (overlays xb+wqb, dead by then)
  float* psums= (float*)(ws + ((size_t)8 << 20));  // 512KB partial sums (overlays wqb tail, dead by then)

  k_cvt<<<dim3(1024), dim3(256), 0, stream>>>(x, wq, wp, xb, wqb, wpb);
  k_gemm_qkv<<<dim3(16, 24), dim3(256), 0, stream>>>(xb, wqb, bq, qarr, karr, varr);
  k_vt<<<dim3(512), dim3(256), 0, stream>>>(varr, vt);
  k_zero<<<dim3(NH * SEQ * HD / 4 / 256), dim3(256), 0, stream>>>(aof);
  k_attn1<<<dim3(4096), dim3(64), 0, stream>>>(qarr, karr, psums);
  k_attn2<<<dim3(4096), dim3(64), 0, stream>>>(qarr, karr, vt, psums, attn, aof);
  k_ored<<<dim3(NH * SEQ * HD / 4 / 256), dim3(256), 0, stream>>>(aof, ao);
  k_gemm_proj<<<dim3(16, 8), dim3(256), 0, stream>>>(ao, wpb, bp, out);
}

// Round 8
// 176.816 us; speedup vs baseline: 1.1975x; 1.1975x over previous
//
#include <hip/hip_runtime.h>
#include <hip/hip_bf16.h>

typedef __hip_bfloat16 bf16;
typedef __attribute__((ext_vector_type(8))) short short8;
typedef __attribute__((ext_vector_type(4))) float f32x4;

#define DEV static __device__ __forceinline__

static constexpr int SEQ = 2048;
static constexpr int DM  = 1024;
static constexpr int NH  = 16;
static constexpr int HD  = 64;
static constexpr int WIN = 2048;
static constexpr int PAD = 1024;   // WIN/2

// async global->LDS, 16B per lane; LDS dest = wave-uniform base + lane*16
DEV void async16(const void* g, void* l) {
  __builtin_amdgcn_global_load_lds(
      (__attribute__((address_space(1))) void*)(g),
      (__attribute__((address_space(3))) void*)(l), 16, 0, 0);
}

// ---------------------------------------------------------------- K0: f32 -> bf16 convert (x, w_qkv, w_proj)
__global__ __launch_bounds__(256) void k_cvt(const float* __restrict__ x,
                                             const float* __restrict__ wq,
                                             const float* __restrict__ wp,
                                             bf16* __restrict__ xb,
                                             bf16* __restrict__ wqb,
                                             bf16* __restrict__ wpb) {
  const int NX = SEQ * DM, NQ = 3 * DM * DM, NP = DM * DM;
  const int tot = (NX + NQ + NP) >> 2;
  const int stride = gridDim.x * 256;
  for (int i = blockIdx.x * 256 + threadIdx.x; i < tot; i += stride) {
    int e = i << 2;
    const float* s; bf16* d; int o;
    if (e < NX)            { s = x;  d = xb;  o = e; }
    else if (e < NX + NQ)  { s = wq; d = wqb; o = e - NX; }
    else                   { s = wp; d = wpb; o = e - NX - NQ; }
    float4 v = *(const float4*)(s + o);
    __align__(8) bf16 t4[4] = {__float2bfloat16(v.x), __float2bfloat16(v.y),
                               __float2bfloat16(v.z), __float2bfloat16(v.w)};
    *(uint2*)(d + o) = *(uint2*)t4;
  }
}

// ---------------------------------------------------------------- shared GEMM core: C[m][n] = sum_k A[m][k]*B[n][k]
DEV void gemm_core(const bf16* __restrict__ A, const bf16* __restrict__ B,
                   int m0, int n0, int K, int tid, bf16* As, bf16* Bs,
                   f32x4 (&acc)[4][4]) {
  const int lane = tid & 63, wid = tid >> 6;
  const int wm = wid >> 1, wn = wid & 1;
  const int l15 = lane & 15, l4 = lane >> 4;
  for (int k0 = 0; k0 < K; k0 += 64) {
    __syncthreads();
    #pragma unroll
    for (int it = 0; it < 4; ++it) {
      int rb = it * 32 + wid * 8;
      int r  = rb + (lane >> 3);
      int c  = (lane & 7) * 8;
      async16(A + (size_t)(m0 + r) * K + k0 + c, As + rb * 64);
      async16(B + (size_t)(n0 + r) * K + k0 + c, Bs + rb * 64);
    }
    asm volatile("s_waitcnt vmcnt(0)" ::: "memory");
    __syncthreads();
    #pragma unroll
    for (int kk = 0; kk < 2; ++kk) {
      short8 a[4], b[4];
      #pragma unroll
      for (int im = 0; im < 4; ++im)
        a[im] = *(const short8*)(As + (wm * 64 + im * 16 + l15) * 64 + kk * 32 + l4 * 8);
      #pragma unroll
      for (int in = 0; in < 4; ++in)
        b[in] = *(const short8*)(Bs + (wn * 64 + in * 16 + l15) * 64 + kk * 32 + l4 * 8);
      #pragma unroll
      for (int im = 0; im < 4; ++im)
        #pragma unroll
        for (int in = 0; in < 4; ++in)
          acc[im][in] = __builtin_amdgcn_mfma_f32_16x16x32_bf16(a[im], b[in], acc[im][in], 0, 0, 0);
    }
  }
}

// ---------------------------------------------------------------- K1: qkv GEMM + scatter to q(scaled)/k/vT
__global__ __launch_bounds__(256) void k_gemm_qkv(const bf16* __restrict__ A,
                                                  const bf16* __restrict__ B,
                                                  const float* __restrict__ bias,
                                                  bf16* __restrict__ qo,
                                                  bf16* __restrict__ ko,
                                                  bf16* __restrict__ vt) {
  __shared__ bf16 As[128 * 64], Bs[128 * 64];
  const int tid = threadIdx.x, lane = tid & 63;
  const int wid = tid >> 6, wm = wid >> 1, wn = wid & 1;
  const int l15 = lane & 15, l4 = lane >> 4;
  const int m0 = blockIdx.x * 128, n0 = blockIdx.y * 128;
  f32x4 acc[4][4] = {};
  gemm_core(A, B, m0, n0, DM, tid, As, Bs, acc);
  #pragma unroll
  for (int im = 0; im < 4; ++im)
    #pragma unroll
    for (int in = 0; in < 4; ++in) {
      int col = n0 + wn * 64 + in * 16 + l15;
      float bval = bias[col];
      int t = col >> 10, h = (col >> 6) & 15, dd = col & 63;
      int row0 = m0 + wm * 64 + im * 16 + l4 * 4;
      if (t == 2) {
        // v transposed directly: vT[h][dd][j], 4 consecutive j -> one 8B store
        __align__(8) bf16 t4[4];
        #pragma unroll
        for (int r = 0; r < 4; ++r)
          t4[r] = __float2bfloat16(acc[im][in][r] + bval);
        *(uint2*)&vt[((size_t)h * HD + dd) * SEQ + row0] = *(uint2*)t4;
      } else {
        #pragma unroll
        for (int r = 0; r < 4; ++r) {
          float v = acc[im][in][r] + bval;
          size_t idx = ((size_t)h * SEQ + row0 + r) * HD + dd;
          // q folded with hd^-0.5 * log2(e) so scores feed exp2 directly
          if (t == 0) qo[idx] = __float2bfloat16(v * 0.18033688011112042f);
          else        ko[idx] = __float2bfloat16(v);
        }
      }
    }
}

// ---------------------------------------------------------------- attn helpers
DEV void stage_kp(const bf16* kbase, int i0, int tt, int lane, bf16* dst) {
  #pragma unroll
  for (int it = 0; it < 4; ++it) {
    int r  = it * 8 + (lane >> 3);
    int cg = lane & 7;
    int jp = i0 + tt * 32 + r;                 // absolute j'
    int krow = jp - PAD;                       // clamp; pad handled analytically
    krow = krow < 0 ? 0 : (krow > SEQ - 1 ? SEQ - 1 : krow);
    int sc = (cg ^ (r & 7)) * 8;               // pre-swizzled global source
    async16(kbase + (size_t)krow * HD + sc, dst + it * 8 * 64);
  }
}

// direct-from-global K fragments (registers), for attn1's reg ping-pong
DEV void load_kf(const bf16* kbase, int i0, int tt, int l15, int l4,
                 short8 (&kf)[2][2]) {
  #pragma unroll
  for (int fn = 0; fn < 2; ++fn) {
    int jp = i0 + tt * 32 + fn * 16 + l15;     // absolute j'
    int krow = jp - PAD;
    krow = krow < 0 ? 0 : (krow > SEQ - 1 ? SEQ - 1 : krow);
    const bf16* rp = kbase + (size_t)krow * HD + l4 * 8;
    kf[fn][0] = *(const short8*)(rp);
    kf[fn][1] = *(const short8*)(rp + 32);
  }
}

// swapped QK (attn1, reg K): sf[fj][fi]: col=i(l15), row=j'(l4*4+r)
DEV void qk_mfma_sw(const short8 (&kf)[2][2], const short8 (&qf)[2][2],
                    f32x4 (&sf)[2][2]) {
  __builtin_amdgcn_s_setprio(1);
  #pragma unroll
  for (int kg = 0; kg < 2; ++kg)
    #pragma unroll
    for (int fj = 0; fj < 2; ++fj)
      #pragma unroll
      for (int fi = 0; fi < 2; ++fi)
        sf[fj][fi] = __builtin_amdgcn_mfma_f32_16x16x32_bf16(kf[fj][kg], qf[fi][kg], sf[fj][fi], 0, 0, 0);
  __builtin_amdgcn_s_setprio(0);
}

DEV int pad_lo(int i0) { int d = PAD - i0; return d <= 0 ? 0 : (d >> 5); }
DEV int pad_hi(int i0) { int t = ((PAD + SEQ - 1 - i0) >> 5) + 1; return t > 65 ? 65 : t; }

// ---------------------------------------------------------------- K2a: partial exp-sums per window chunk (+ aof zero)
__global__ __launch_bounds__(64) void k_attn1(const bf16* __restrict__ q,
                                              const bf16* __restrict__ kkk,
                                              float* __restrict__ psums,
                                              float* __restrict__ aof) {
  const int c  = blockIdx.x & 3;
  const int i0 = ((blockIdx.x >> 2) & 63) << 5;
  const int h  = blockIdx.x >> 8;
  const int lane = threadIdx.x;
  const int l15 = lane & 15, l4 = lane >> 4;

  // zero this block's disjoint 2KB slice of aof (runs before attn2 in stream)
  {
    f32x4 z = {0.f, 0.f, 0.f, 0.f};
    ((f32x4*)aof)[blockIdx.x * 128 + lane]      = z;
    ((f32x4*)aof)[blockIdx.x * 128 + 64 + lane] = z;
  }

  constexpr int st[5] = {0, 16, 32, 48, 65};
  const int lo_g = pad_lo(i0), hi_g = pad_hi(i0);
  int lo = st[c] > lo_g ? st[c] : lo_g;
  int hi = st[c + 1] < hi_g ? st[c + 1] : hi_g;

  short8 qf[2][2];
  #pragma unroll
  for (int fi = 0; fi < 2; ++fi)
    #pragma unroll
    for (int kg = 0; kg < 2; ++kg)
      qf[fi][kg] = *(const short8*)&q[((size_t)h * SEQ + i0 + fi * 16 + l15) * HD + kg * 32 + l4 * 8];

  const bf16* kbase = kkk + (size_t)h * SEQ * HD;

  float psum[2] = {0.f, 0.f};
  auto acc_tile = [&](const f32x4 (&sf)[2][2], int tt) {
    const bool interior = (tt >= 1) && (tt <= 63) &&
                          (i0 + tt * 32 >= PAD) && (i0 + tt * 32 + 31 < PAD + SEQ);
    if (interior) {
      #pragma unroll
      for (int fj = 0; fj < 2; ++fj)
        #pragma unroll
        for (int r = 0; r < 4; ++r) {
          psum[0] += __builtin_amdgcn_exp2f(sf[fj][0][r]);
          psum[1] += __builtin_amdgcn_exp2f(sf[fj][1][r]);
        }
    } else {
      #pragma unroll
      for (int fj = 0; fj < 2; ++fj)
        #pragma unroll
        for (int r = 0; r < 4; ++r) {
          int jj = tt * 32 + fj * 16 + l4 * 4 + r;   // local j'
          int jp = i0 + jj;                          // absolute j'
          bool pad = (jp < PAD) || (jp >= PAD + SEQ);
          #pragma unroll
          for (int fi = 0; fi < 2; ++fi) {
            int iloc = fi * 16 + l15;
            float e = pad ? 1.0f : __builtin_amdgcn_exp2f(sf[fj][fi][r]);
            if ((unsigned)(jj - iloc) < (unsigned)WIN) psum[fi] += e;
          }
        }
    }
  };

  // register ping-pong prefetch pipeline (no LDS)
  short8 kA[2][2], kB[2][2];
  if (lo < hi) load_kf(kbase, i0, lo, l15, l4, kA);
  for (int tt = lo; tt < hi; ++tt) {
    if (((tt - lo) & 1) == 0) {
      if (tt + 1 < hi) load_kf(kbase, i0, tt + 1, l15, l4, kB);
      f32x4 sf[2][2] = {};
      qk_mfma_sw(kA, qf, sf);
      acc_tile(sf, tt);
    } else {
      if (tt + 1 < hi) load_kf(kbase, i0, tt + 1, l15, l4, kA);
      f32x4 sf[2][2] = {};
      qk_mfma_sw(kB, qf, sf);
      acc_tile(sf, tt);
    }
  }

  float r0 = psum[0];
  r0 += __shfl_xor(r0, 16); r0 += __shfl_xor(r0, 32);
  float r1 = psum[1];
  r1 += __shfl_xor(r1, 16); r1 += __shfl_xor(r1, 32);
  if (lane < 32) {
    int i_abs = i0 + lane;
    float s = (lane < 16) ? r0 : r1;
    if (c == 0) {
      int cl = i0 + lo_g * 32 - i_abs; if (cl < 0) cl = 0;
      int cr = i_abs + WIN - (i0 + hi_g * 32); if (cr < 0) cr = 0;
      s += (float)(cl + cr);                  // analytic all-pad contribution
    }
    psums[((size_t)c * NH + h) * SEQ + i_abs] = s;
  }
}

// ---------------------------------------------------------------- K2b: recompute + normalize + ALIGNED attn flush + PV
// (round-5 structure: KP async-LDS double buffer, counted vmcnt, nt flush)
__global__ __launch_bounds__(64) void k_attn2(const bf16* __restrict__ q,
                                              const bf16* __restrict__ kkk,
                                              const bf16* __restrict__ vT,
                                              const float* __restrict__ psums,
                                              float* __restrict__ attn,
                                              float* __restrict__ aof) {
  const int c  = blockIdx.x & 3;
  const int i0 = ((blockIdx.x >> 2) & 63) << 5;
  const int h  = blockIdx.x >> 8;
  const int lane = threadIdx.x;
  const int l15 = lane & 15, l4 = lane >> 4;
  const int c0 = c * 16, c1 = c0 + 16;
  const int lo_g = pad_lo(i0), hi_g = pad_hi(i0);

  __shared__ bf16 KP[2][32 * 64];
  __shared__ float JF[32 * 64];    // j-aligned f32 ring; 4-float groups XOR-swizzled by row

  float inv[2][4];
  #pragma unroll
  for (int fm = 0; fm < 2; ++fm)
    #pragma unroll
    for (int r = 0; r < 4; ++r) {
      int row = i0 + fm * 16 + l4 * 4 + r;
      float s = 0.f;
      #pragma unroll
      for (int cc = 0; cc < 4; ++cc)
        s += psums[((size_t)cc * NH + h) * SEQ + row];
      inv[fm][r] = __builtin_amdgcn_rcpf(s);
    }

  short8 qf[2][2];
  #pragma unroll
  for (int fm = 0; fm < 2; ++fm)
    #pragma unroll
    for (int kg = 0; kg < 2; ++kg)
      qf[fm][kg] = *(const short8*)&q[((size_t)h * SEQ + i0 + fm * 16 + l15) * HD + kg * 32 + l4 * 8];

  const bf16* kbase = kkk + (size_t)h * SEQ * HD;
  const bf16* vbase = vT + (size_t)h * HD * SEQ;
  float* abase = attn + (size_t)(h * SEQ + i0) * WIN;

  f32x4 oacc[2][4] = {};
  stage_kp(kbase, i0, c0, lane, KP[0]);        // c0 even -> buf 0
  for (int tt = c0; tt <= c1; ++tt) {
    short8 bv[4];
    if (tt > c0) {
      int jb = (tt - 1) * 32;
      #pragma unroll
      for (int nd = 0; nd < 4; ++nd)
        bv[nd] = *(const short8*)&vbase[(size_t)(nd * 16 + l15) * SEQ + jb + l4 * 8];
    }
    int nxt = (tt < c1) ? tt + 1 : tt;
    stage_kp(kbase, i0, nxt, lane, KP[(tt + 1) & 1]);
    // counted wait for stage(tt): younger = stores(t-1)[4]+bv[4]+stage(t+1)[4]
    if (tt == c0)          asm volatile("s_waitcnt vmcnt(4)" ::: "memory");
    else if (tt == c0 + 1) asm volatile("s_waitcnt vmcnt(8)" ::: "memory");
    else                   asm volatile("s_waitcnt vmcnt(12)" ::: "memory");

    const bool fp = (tt < lo_g) || (tt >= hi_g);   // all-pad tile: score==0
    f32x4 sf[2][2] = {};
    if (!fp) {
      const bf16* KPb = KP[tt & 1];
      __builtin_amdgcn_s_setprio(1);
      #pragma unroll
      for (int kg = 0; kg < 2; ++kg) {
        short8 kfr[2];
        #pragma unroll
        for (int fn = 0; fn < 2; ++fn) {
          int jl = fn * 16 + l15;
          int pg = (kg * 4 + l4) ^ (jl & 7);
          kfr[fn] = *(const short8*)&KPb[jl * 64 + pg * 8];
        }
        #pragma unroll
        for (int fm = 0; fm < 2; ++fm)
          #pragma unroll
          for (int fn = 0; fn < 2; ++fn)
            sf[fm][fn] = __builtin_amdgcn_mfma_f32_16x16x32_bf16(qf[fm][kg], kfr[fn], sf[fm][fn], 0, 0, 0);
      }
      __builtin_amdgcn_s_setprio(0);
    }

    // re-bin diagonal tile into j-aligned JF ring
    const bool allv = (i0 + tt * 32 >= PAD) && (i0 + tt * 32 + 31 < PAD + SEQ);
    #pragma unroll
    for (int fm = 0; fm < 2; ++fm)
      #pragma unroll
      for (int fn = 0; fn < 2; ++fn) {
        int J0 = tt * 32 + fn * 16 + l15;          // local j' (col)
        bool padc = fp || (!allv && ((i0 + J0 < PAD) || (i0 + J0 >= PAD + SEQ)));
        #pragma unroll
        for (int r = 0; r < 4; ++r) {
          int row = fm * 16 + l4 * 4 + r;          // local i
          float e = padc ? 1.0f : __builtin_amdgcn_exp2f(sf[fm][fn][r]);
          float val = e * inv[fm][r];
          int j6 = (J0 - row) & 63;                // ring position
          int pgrp = (j6 >> 2) ^ ((row & 7) << 1);
          JF[row * 64 + pgrp * 4 + (j6 & 3)] = val;
        }
      }

    if (tt > c0) {
      const int g = (tt - 1) & 1;                  // ring slot of completed j-tile
      const int Jb = (tt - 1) * 32;
      #pragma unroll
      for (int s = 0; s < 4; ++s) {
        int row = s * 8 + (lane >> 3);
        int c8 = lane & 7;
        int pgrp = (g * 8 + c8) ^ ((row & 7) << 1);
        f32x4 vv = *(const f32x4*)&JF[row * 64 + pgrp * 4];
        __builtin_nontemporal_store(vv, (f32x4*)(abase + (size_t)row * WIN + Jb + c8 * 4));
      }
      short8 af[2];
      #pragma unroll
      for (int fm = 0; fm < 2; ++fm) {
        int row = fm * 16 + l15;
        int pg0 = (g * 8 + l4 * 2) ^ ((row & 7) << 1);
        const float* p = &JF[row * 64 + pg0 * 4];
        union { unsigned short u[8]; short8 v; } tmp;
        #pragma unroll
        for (int e = 0; e < 8; ++e)
          tmp.u[e] = __bfloat16_as_ushort(__float2bfloat16(p[e]));
        af[fm] = tmp.v;
      }
      __builtin_amdgcn_s_setprio(1);
      #pragma unroll
      for (int fm = 0; fm < 2; ++fm)
        #pragma unroll
        for (int nd = 0; nd < 4; ++nd)
          oacc[fm][nd] = __builtin_amdgcn_mfma_f32_16x16x32_bf16(af[fm], bv[nd], oacc[fm][nd], 0, 0, 0);
      __builtin_amdgcn_s_setprio(0);
    }
  }
  #pragma unroll
  for (int fm = 0; fm < 2; ++fm)
    #pragma unroll
    for (int nd = 0; nd < 4; ++nd)
      #pragma unroll
      for (int r = 0; r < 4; ++r) {
        int i  = i0 + fm * 16 + l4 * 4 + r;
        int dd = nd * 16 + l15;
        atomicAdd(&aof[((size_t)h * SEQ + i) * HD + dd], oacc[fm][nd][r]);
      }
}

// ---------------------------------------------------------------- K2c: aof f32 [h][i][dd] -> ao bf16 [i][h*64+dd]
__global__ __launch_bounds__(256) void k_ored(const float* __restrict__ aof,
                                              bf16* __restrict__ ao) {
  int f = blockIdx.x * 256 + threadIdx.x;
  int e = f << 2;
  int h  = e >> 17;
  int i  = (e >> 6) & (SEQ - 1);
  int dd = e & 63;
  float4 v = ((const float4*)aof)[f];
  __align__(8) bf16 t4[4] = {__float2bfloat16(v.x), __float2bfloat16(v.y),
                             __float2bfloat16(v.z), __float2bfloat16(v.w)};
  *(uint2*)&ao[(size_t)i * DM + h * HD + dd] = *(uint2*)t4;
}

// ---------------------------------------------------------------- K4: proj GEMM -> d_out (f32)
__global__ __launch_bounds__(256) void k_gemm_proj(const bf16* __restrict__ A,
                                                   const bf16* __restrict__ B,
                                                   const float* __restrict__ bias,
                                                   float* __restrict__ out) {
  __shared__ bf16 As[128 * 64], Bs[128 * 64];
  const int tid = threadIdx.x, lane = tid & 63;
  const int wid = tid >> 6, wm = wid >> 1, wn = wid & 1;
  const int l15 = lane & 15, l4 = lane >> 4;
  const int m0 = blockIdx.x * 128, n0 = blockIdx.y * 128;
  f32x4 acc[4][4] = {};
  gemm_core(A, B, m0, n0, DM, tid, As, Bs, acc);
  #pragma unroll
  for (int im = 0; im < 4; ++im)
    #pragma unroll
    for (int in = 0; in < 4; ++in) {
      int col = n0 + wn * 64 + in * 16 + l15;
      float bval = bias[col];
      #pragma unroll
      for (int r = 0; r < 4; ++r) {
        int row = m0 + wm * 64 + im * 16 + l4 * 4 + r;
        out[(size_t)row * DM + col] = acc[im][in][r] + bval;
      }
    }
}

// ---------------------------------------------------------------- launch
extern "C" void kernel_launch(void* const* d_in, const int* in_sizes, int n_in,
                              void* d_out, int out_size, void* d_ws, size_t ws_size,
                              hipStream_t stream) {
  (void)in_sizes; (void)n_in; (void)out_size; (void)ws_size;
  const float* x  = (const float*)d_in[0];
  const float* wq = (const float*)d_in[1];
  const float* bq = (const float*)d_in[2];
  const float* wp = (const float*)d_in[3];
  const float* bp = (const float*)d_in[4];
  float* out  = (float*)d_out;
  float* attn = out + (size_t)SEQ * DM;

  char* ws = (char*)d_ws;
  bf16* xb    = (bf16*)(ws + (size_t) 0);          // 4 MB  x bf16            [dead after qkv gemm]
  bf16* wqb   = (bf16*)(ws + ((size_t)4  << 20));  // 6 MB  w_qkv bf16        [dead after qkv gemm]
  bf16* wpb   = (bf16*)(ws + ((size_t)10 << 20));  // 2 MB  w_proj bf16
  bf16* qarr  = (bf16*)(ws + ((size_t)12 << 20));  // 4 MB  q [h][i][d] (scale*log2e folded)
  bf16* karr  = (bf16*)(ws + ((size_t)16 << 20));  // 4 MB  k [h][j][d]
  bf16* vt    = (bf16*)(ws + ((size_t)24 << 20));  // 4 MB  vT [h][d][j] (written by qkv epilogue)
  bf16* ao    = (bf16*)(ws + ((size_t)28 << 20));  // 4 MB  attn-out rows [i][h*64+d]
  float* aof  = (float*)(ws + (size_t)0);          // 8 MB  f32 O accum (overlays xb+wqb, dead by then)
  float* psums= (float*)(ws + ((size_t)8 << 20));  // 512KB partial sums (overlays wqb tail, dead by then)

  k_cvt<<<dim3(1024), dim3(256), 0, stream>>>(x, wq, wp, xb, wqb, wpb);
  k_gemm_qkv<<<dim3(16, 24), dim3(256), 0, stream>>>(xb, wqb, bq, qarr, karr, vt);
  k_attn1<<<dim3(4096), dim3(64), 0, stream>>>(qarr, karr, psums, aof);
  k_attn2<<<dim3(4096), dim3(64), 0, stream>>>(qarr, karr, vt, psums, attn, aof);
  k_ored<<<dim3(NH * SEQ * HD / 4 / 256), dim3(256), 0, stream>>>(aof, ao);
  k_gemm_proj<<<dim3(16, 8), dim3(256), 0, stream>>>(ao, wpb, bp, out);
}

// Round 9
// 162.641 us; speedup vs baseline: 1.3019x; 1.0872x over previous
//
#include <hip/hip_runtime.h>
#include <hip/hip_bf16.h>

typedef __hip_bfloat16 bf16;
typedef __attribute__((ext_vector_type(8))) short short8;
typedef __attribute__((ext_vector_type(4))) float f32x4;

#define DEV static __device__ __forceinline__

static constexpr int SEQ = 2048;
static constexpr int DM  = 1024;
static constexpr int NH  = 16;
static constexpr int HD  = 64;
static constexpr int WIN = 2048;
static constexpr int PAD = 1024;   // WIN/2

// async global->LDS, 16B per lane; LDS dest = wave-uniform base + lane*16
DEV void async16(const void* g, void* l) {
  __builtin_amdgcn_global_load_lds(
      (__attribute__((address_space(1))) void*)(g),
      (__attribute__((address_space(3))) void*)(l), 16, 0, 0);
}

// ---------------------------------------------------------------- K0: f32 -> bf16 convert (x, w_qkv, w_proj)
__global__ __launch_bounds__(256) void k_cvt(const float* __restrict__ x,
                                             const float* __restrict__ wq,
                                             const float* __restrict__ wp,
                                             bf16* __restrict__ xb,
                                             bf16* __restrict__ wqb,
                                             bf16* __restrict__ wpb) {
  const int NX = SEQ * DM, NQ = 3 * DM * DM, NP = DM * DM;
  const int tot = (NX + NQ + NP) >> 2;
  const int stride = gridDim.x * 256;
  for (int i = blockIdx.x * 256 + threadIdx.x; i < tot; i += stride) {
    int e = i << 2;
    const float* s; bf16* d; int o;
    if (e < NX)            { s = x;  d = xb;  o = e; }
    else if (e < NX + NQ)  { s = wq; d = wqb; o = e - NX; }
    else                   { s = wp; d = wpb; o = e - NX - NQ; }
    float4 v = *(const float4*)(s + o);
    __align__(8) bf16 t4[4] = {__float2bfloat16(v.x), __float2bfloat16(v.y),
                               __float2bfloat16(v.z), __float2bfloat16(v.w)};
    *(uint2*)(d + o) = *(uint2*)t4;
  }
}

// ---------------------------------------------------------------- shared GEMM core: C[m][n] = sum_k A[m][k]*B[n][k]
DEV void gemm_core(const bf16* __restrict__ A, const bf16* __restrict__ B,
                   int m0, int n0, int K, int tid, bf16* As, bf16* Bs,
                   f32x4 (&acc)[4][4]) {
  const int lane = tid & 63, wid = tid >> 6;
  const int wm = wid >> 1, wn = wid & 1;
  const int l15 = lane & 15, l4 = lane >> 4;
  for (int k0 = 0; k0 < K; k0 += 64) {
    __syncthreads();
    #pragma unroll
    for (int it = 0; it < 4; ++it) {
      int rb = it * 32 + wid * 8;
      int r  = rb + (lane >> 3);
      int c  = (lane & 7) * 8;
      async16(A + (size_t)(m0 + r) * K + k0 + c, As + rb * 64);
      async16(B + (size_t)(n0 + r) * K + k0 + c, Bs + rb * 64);
    }
    asm volatile("s_waitcnt vmcnt(0)" ::: "memory");
    __syncthreads();
    #pragma unroll
    for (int kk = 0; kk < 2; ++kk) {
      short8 a[4], b[4];
      #pragma unroll
      for (int im = 0; im < 4; ++im)
        a[im] = *(const short8*)(As + (wm * 64 + im * 16 + l15) * 64 + kk * 32 + l4 * 8);
      #pragma unroll
      for (int in = 0; in < 4; ++in)
        b[in] = *(const short8*)(Bs + (wn * 64 + in * 16 + l15) * 64 + kk * 32 + l4 * 8);
      #pragma unroll
      for (int im = 0; im < 4; ++im)
        #pragma unroll
        for (int in = 0; in < 4; ++in)
          acc[im][in] = __builtin_amdgcn_mfma_f32_16x16x32_bf16(a[im], b[in], acc[im][in], 0, 0, 0);
    }
  }
}

// ---------------------------------------------------------------- K1: qkv GEMM + scatter to q(scaled)/k/vT
__global__ __launch_bounds__(256) void k_gemm_qkv(const bf16* __restrict__ A,
                                                  const bf16* __restrict__ B,
                                                  const float* __restrict__ bias,
                                                  bf16* __restrict__ qo,
                                                  bf16* __restrict__ ko,
                                                  bf16* __restrict__ vt) {
  __shared__ bf16 As[128 * 64], Bs[128 * 64];
  const int tid = threadIdx.x, lane = tid & 63;
  const int wid = tid >> 6, wm = wid >> 1, wn = wid & 1;
  const int l15 = lane & 15, l4 = lane >> 4;
  const int m0 = blockIdx.x * 128, n0 = blockIdx.y * 128;
  f32x4 acc[4][4] = {};
  gemm_core(A, B, m0, n0, DM, tid, As, Bs, acc);
  #pragma unroll
  for (int im = 0; im < 4; ++im)
    #pragma unroll
    for (int in = 0; in < 4; ++in) {
      int col = n0 + wn * 64 + in * 16 + l15;
      float bval = bias[col];
      int t = col >> 10, h = (col >> 6) & 15, dd = col & 63;
      int row0 = m0 + wm * 64 + im * 16 + l4 * 4;
      if (t == 2) {
        // v transposed directly: vT[h][dd][j], 4 consecutive j -> one 8B store
        __align__(8) bf16 t4[4];
        #pragma unroll
        for (int r = 0; r < 4; ++r)
          t4[r] = __float2bfloat16(acc[im][in][r] + bval);
        *(uint2*)&vt[((size_t)h * HD + dd) * SEQ + row0] = *(uint2*)t4;
      } else {
        #pragma unroll
        for (int r = 0; r < 4; ++r) {
          float v = acc[im][in][r] + bval;
          size_t idx = ((size_t)h * SEQ + row0 + r) * HD + dd;
          // q folded with hd^-0.5 * log2(e) so scores feed exp2 directly
          if (t == 0) qo[idx] = __float2bfloat16(v * 0.18033688011112042f);
          else        ko[idx] = __float2bfloat16(v);
        }
      }
    }
}

// ---------------------------------------------------------------- attn helpers
DEV void stage_kp(const bf16* kbase, int i0, int tt, int lane, bf16* dst) {
  #pragma unroll
  for (int it = 0; it < 4; ++it) {
    int r  = it * 8 + (lane >> 3);
    int cg = lane & 7;
    int jp = i0 + tt * 32 + r;                 // absolute j'
    int krow = jp - PAD;                       // clamp; pad handled analytically
    krow = krow < 0 ? 0 : (krow > SEQ - 1 ? SEQ - 1 : krow);
    int sc = (cg ^ (r & 7)) * 8;               // pre-swizzled global source
    async16(kbase + (size_t)krow * HD + sc, dst + it * 8 * 64);
  }
}

// LDS K -> MFMA, unswapped: sf[fm][fn]: col=j'(l15), row=i(l4*4+r)
DEV void qk_mfma_lds(const bf16* KPb, const short8 (&qf)[2][2], int l15, int l4,
                     f32x4 (&sf)[2][2]) {
  __builtin_amdgcn_s_setprio(1);
  #pragma unroll
  for (int kg = 0; kg < 2; ++kg) {
    short8 kfr[2];
    #pragma unroll
    for (int fn = 0; fn < 2; ++fn) {
      int jl = fn * 16 + l15;
      int pg = (kg * 4 + l4) ^ (jl & 7);
      kfr[fn] = *(const short8*)&KPb[jl * 64 + pg * 8];
    }
    #pragma unroll
    for (int fm = 0; fm < 2; ++fm)
      #pragma unroll
      for (int fn = 0; fn < 2; ++fn)
        sf[fm][fn] = __builtin_amdgcn_mfma_f32_16x16x32_bf16(qf[fm][kg], kfr[fn], sf[fm][fn], 0, 0, 0);
  }
  __builtin_amdgcn_s_setprio(0);
}

// swapped variant for attn1 (LDS K): sf[fj][fi]: col=i(l15), row=j'(l4*4+r)
DEV void qk_mfma_lds_sw(const bf16* KPb, const short8 (&qf)[2][2], int l15, int l4,
                        f32x4 (&sf)[2][2]) {
  __builtin_amdgcn_s_setprio(1);
  #pragma unroll
  for (int kg = 0; kg < 2; ++kg) {
    short8 kfr[2];
    #pragma unroll
    for (int fj = 0; fj < 2; ++fj) {
      int jl = fj * 16 + l15;
      int pg = (kg * 4 + l4) ^ (jl & 7);
      kfr[fj] = *(const short8*)&KPb[jl * 64 + pg * 8];
    }
    #pragma unroll
    for (int fj = 0; fj < 2; ++fj)
      #pragma unroll
      for (int fi = 0; fi < 2; ++fi)
        sf[fj][fi] = __builtin_amdgcn_mfma_f32_16x16x32_bf16(kfr[fj], qf[fi][kg], sf[fj][fi], 0, 0, 0);
  }
  __builtin_amdgcn_s_setprio(0);
}

DEV int pad_lo(int i0) { int d = PAD - i0; return d <= 0 ? 0 : (d >> 5); }
DEV int pad_hi(int i0) { int t = ((PAD + SEQ - 1 - i0) >> 5) + 1; return t > 65 ? 65 : t; }

// ---------------------------------------------------------------- K2a: partial exp-sums, 4 chunk-waves per 256-thread block
__global__ __launch_bounds__(256) void k_attn1(const bf16* __restrict__ q,
                                               const bf16* __restrict__ kkk,
                                               float* __restrict__ psums,
                                               float* __restrict__ aof) {
  const int h  = blockIdx.x >> 6;
  const int i0 = (blockIdx.x & 63) << 5;
  const int tid = threadIdx.x;
  const int c = tid >> 6;                     // wave = chunk
  const int lane = tid & 63;
  const int l15 = lane & 15, l4 = lane >> 4;

  __shared__ bf16 KP[4][2][32 * 64];          // per-wave double buffer (32 KB)

  // zero this block's disjoint 8KB slice of aof (runs before attn2 in stream)
  {
    f32x4 z = {0.f, 0.f, 0.f, 0.f};
    size_t zb = ((size_t)h * SEQ + i0) * (HD / 4);
    ((f32x4*)aof)[zb + tid]       = z;
    ((f32x4*)aof)[zb + 256 + tid] = z;
  }

  constexpr int st[5] = {0, 16, 32, 48, 65};
  const int lo_g = pad_lo(i0), hi_g = pad_hi(i0);
  int lo = st[c] > lo_g ? st[c] : lo_g;
  int hi = st[c + 1] < hi_g ? st[c + 1] : hi_g;

  short8 qf[2][2];
  #pragma unroll
  for (int fi = 0; fi < 2; ++fi)
    #pragma unroll
    for (int kg = 0; kg < 2; ++kg)
      qf[fi][kg] = *(const short8*)&q[((size_t)h * SEQ + i0 + fi * 16 + l15) * HD + kg * 32 + l4 * 8];

  const bf16* kbase = kkk + (size_t)h * SEQ * HD;

  float psum[2] = {0.f, 0.f};
  if (lo < hi) {
    stage_kp(kbase, i0, lo, lane, KP[c][lo & 1]);
    for (int tt = lo; tt < hi; ++tt) {
      int nxt = (tt + 1 < hi) ? tt + 1 : tt;
      stage_kp(kbase, i0, nxt, lane, KP[c][(tt + 1) & 1]);
      asm volatile("s_waitcnt vmcnt(4)" ::: "memory");
      f32x4 sf[2][2] = {};
      qk_mfma_lds_sw(KP[c][tt & 1], qf, l15, l4, sf);
      const bool interior = (tt >= 1) && (tt <= 63) &&
                            (i0 + tt * 32 >= PAD) && (i0 + tt * 32 + 31 < PAD + SEQ);
      if (interior) {
        #pragma unroll
        for (int fj = 0; fj < 2; ++fj)
          #pragma unroll
          for (int r = 0; r < 4; ++r) {
            psum[0] += __builtin_amdgcn_exp2f(sf[fj][0][r]);
            psum[1] += __builtin_amdgcn_exp2f(sf[fj][1][r]);
          }
      } else {
        #pragma unroll
        for (int fj = 0; fj < 2; ++fj)
          #pragma unroll
          for (int r = 0; r < 4; ++r) {
            int jj = tt * 32 + fj * 16 + l4 * 4 + r;   // local j'
            int jp = i0 + jj;                          // absolute j'
            bool pad = (jp < PAD) || (jp >= PAD + SEQ);
            #pragma unroll
            for (int fi = 0; fi < 2; ++fi) {
              int iloc = fi * 16 + l15;
              float e = pad ? 1.0f : __builtin_amdgcn_exp2f(sf[fj][fi][r]);
              if ((unsigned)(jj - iloc) < (unsigned)WIN) psum[fi] += e;
            }
          }
      }
    }
  }
  float r0 = psum[0];
  r0 += __shfl_xor(r0, 16); r0 += __shfl_xor(r0, 32);
  float r1 = psum[1];
  r1 += __shfl_xor(r1, 16); r1 += __shfl_xor(r1, 32);
  if (lane < 32) {
    int i_abs = i0 + lane;
    float s = (lane < 16) ? r0 : r1;
    if (c == 0) {
      int cl = i0 + lo_g * 32 - i_abs; if (cl < 0) cl = 0;
      int cr = i_abs + WIN - (i0 + hi_g * 32); if (cr < 0) cr = 0;
      s += (float)(cl + cr);                  // analytic all-pad contribution
    }
    psums[((size_t)c * NH + h) * SEQ + i_abs] = s;
  }
}

// ---------------------------------------------------------------- K2b: recompute + normalize + aligned flush + PV
// 4 chunk-waves per 256-thread block; per-wave private KP/JF; no barriers.
__global__ __launch_bounds__(256) void k_attn2(const bf16* __restrict__ q,
                                               const bf16* __restrict__ kkk,
                                               const bf16* __restrict__ vT,
                                               const float* __restrict__ psums,
                                               float* __restrict__ attn,
                                               float* __restrict__ aof) {
  const int h  = blockIdx.x >> 6;
  const int i0 = (blockIdx.x & 63) << 5;
  const int tid = threadIdx.x;
  const int c = tid >> 6;                     // wave = chunk
  const int lane = tid & 63;
  const int l15 = lane & 15, l4 = lane >> 4;
  const int c0 = c * 16, c1 = c0 + 16;
  const int lo_g = pad_lo(i0), hi_g = pad_hi(i0);

  __shared__ bf16 KP[4][2][32 * 64];          // 32 KB
  __shared__ float JF[4][32 * 64];            // 32 KB, per-wave j-aligned f32 ring

  float inv[2][4];
  #pragma unroll
  for (int fm = 0; fm < 2; ++fm)
    #pragma unroll
    for (int r = 0; r < 4; ++r) {
      int row = i0 + fm * 16 + l4 * 4 + r;
      float s = 0.f;
      #pragma unroll
      for (int cc = 0; cc < 4; ++cc)
        s += psums[((size_t)cc * NH + h) * SEQ + row];
      inv[fm][r] = __builtin_amdgcn_rcpf(s);
    }

  short8 qf[2][2];
  #pragma unroll
  for (int fm = 0; fm < 2; ++fm)
    #pragma unroll
    for (int kg = 0; kg < 2; ++kg)
      qf[fm][kg] = *(const short8*)&q[((size_t)h * SEQ + i0 + fm * 16 + l15) * HD + kg * 32 + l4 * 8];

  const bf16* kbase = kkk + (size_t)h * SEQ * HD;
  const bf16* vbase = vT + (size_t)h * HD * SEQ;
  float* abase = attn + (size_t)(h * SEQ + i0) * WIN;
  float* JFW = JF[c];

  f32x4 oacc[2][4] = {};
  stage_kp(kbase, i0, c0, lane, KP[c][0]);     // c0 even -> buf 0
  for (int tt = c0; tt <= c1; ++tt) {
    short8 bv[4];
    if (tt > c0) {
      int jb = (tt - 1) * 32;
      #pragma unroll
      for (int nd = 0; nd < 4; ++nd)
        bv[nd] = *(const short8*)&vbase[(size_t)(nd * 16 + l15) * SEQ + jb + l4 * 8];
    }
    int nxt = (tt < c1) ? tt + 1 : tt;
    stage_kp(kbase, i0, nxt, lane, KP[c][(tt + 1) & 1]);
    // counted wait for stage(tt): younger = stores(t-1)[4]+bv[4]+stage(t+1)[4]
    if (tt == c0)          asm volatile("s_waitcnt vmcnt(4)" ::: "memory");
    else if (tt == c0 + 1) asm volatile("s_waitcnt vmcnt(8)" ::: "memory");
    else                   asm volatile("s_waitcnt vmcnt(12)" ::: "memory");

    const bool fp = (tt < lo_g) || (tt >= hi_g);   // all-pad tile: score==0
    f32x4 sf[2][2] = {};
    if (!fp) qk_mfma_lds(KP[c][tt & 1], qf, l15, l4, sf);

    // re-bin diagonal tile into j-aligned JF ring
    const bool allv = (i0 + tt * 32 >= PAD) && (i0 + tt * 32 + 31 < PAD + SEQ);
    #pragma unroll
    for (int fm = 0; fm < 2; ++fm)
      #pragma unroll
      for (int fn = 0; fn < 2; ++fn) {
        int J0 = tt * 32 + fn * 16 + l15;          // local j' (col)
        bool padc = fp || (!allv && ((i0 + J0 < PAD) || (i0 + J0 >= PAD + SEQ)));
        #pragma unroll
        for (int r = 0; r < 4; ++r) {
          int row = fm * 16 + l4 * 4 + r;          // local i
          float e = padc ? 1.0f : __builtin_amdgcn_exp2f(sf[fm][fn][r]);
          float val = e * inv[fm][r];
          int j6 = (J0 - row) & 63;                // ring position
          int pgrp = (j6 >> 2) ^ ((row & 7) << 1);
          JFW[row * 64 + pgrp * 4 + (j6 & 3)] = val;
        }
      }

    if (tt > c0) {
      const int g = (tt - 1) & 1;                  // ring slot of completed j-tile
      const int Jb = (tt - 1) * 32;
      #pragma unroll
      for (int s = 0; s < 4; ++s) {
        int row = s * 8 + (lane >> 3);
        int c8 = lane & 7;
        int pgrp = (g * 8 + c8) ^ ((row & 7) << 1);
        f32x4 vv = *(const f32x4*)&JFW[row * 64 + pgrp * 4];
        __builtin_nontemporal_store(vv, (f32x4*)(abase + (size_t)row * WIN + Jb + c8 * 4));
      }
      short8 af[2];
      #pragma unroll
      for (int fm = 0; fm < 2; ++fm) {
        int row = fm * 16 + l15;
        int pg0 = (g * 8 + l4 * 2) ^ ((row & 7) << 1);
        const float* p = &JFW[row * 64 + pg0 * 4];
        union { unsigned short u[8]; short8 v; } tmp;
        #pragma unroll
        for (int e = 0; e < 8; ++e)
          tmp.u[e] = __bfloat16_as_ushort(__float2bfloat16(p[e]));
        af[fm] = tmp.v;
      }
      __builtin_amdgcn_s_setprio(1);
      #pragma unroll
      for (int fm = 0; fm < 2; ++fm)
        #pragma unroll
        for (int nd = 0; nd < 4; ++nd)
          oacc[fm][nd] = __builtin_amdgcn_mfma_f32_16x16x32_bf16(af[fm], bv[nd], oacc[fm][nd], 0, 0, 0);
      __builtin_amdgcn_s_setprio(0);
    }
  }
  #pragma unroll
  for (int fm = 0; fm < 2; ++fm)
    #pragma unroll
    for (int nd = 0; nd < 4; ++nd)
      #pragma unroll
      for (int r = 0; r < 4; ++r) {
        int i  = i0 + fm * 16 + l4 * 4 + r;
        int dd = nd * 16 + l15;
        atomicAdd(&aof[((size_t)h * SEQ + i) * HD + dd], oacc[fm][nd][r]);
      }
}

// ---------------------------------------------------------------- K2c: aof f32 [h][i][dd] -> ao bf16 [i][h*64+dd]
__global__ __launch_bounds__(256) void k_ored(const float* __restrict__ aof,
                                              bf16* __restrict__ ao) {
  int f = blockIdx.x * 256 + threadIdx.x;
  int e = f << 2;
  int h  = e >> 17;
  int i  = (e >> 6) & (SEQ - 1);
  int dd = e & 63;
  float4 v = ((const float4*)aof)[f];
  __align__(8) bf16 t4[4] = {__float2bfloat16(v.x), __float2bfloat16(v.y),
                             __float2bfloat16(v.z), __float2bfloat16(v.w)};
  *(uint2*)&ao[(size_t)i * DM + h * HD + dd] = *(uint2*)t4;
}

// ---------------------------------------------------------------- K4: proj GEMM -> d_out (f32)
__global__ __launch_bounds__(256) void k_gemm_proj(const bf16* __restrict__ A,
                                                   const bf16* __restrict__ B,
                                                   const float* __restrict__ bias,
                                                   float* __restrict__ out) {
  __shared__ bf16 As[128 * 64], Bs[128 * 64];
  const int tid = threadIdx.x, lane = tid & 63;
  const int wid = tid >> 6, wm = wid >> 1, wn = wid & 1;
  const int l15 = lane & 15, l4 = lane >> 4;
  const int m0 = blockIdx.x * 128, n0 = blockIdx.y * 128;
  f32x4 acc[4][4] = {};
  gemm_core(A, B, m0, n0, DM, tid, As, Bs, acc);
  #pragma unroll
  for (int im = 0; im < 4; ++im)
    #pragma unroll
    for (int in = 0; in < 4; ++in) {
      int col = n0 + wn * 64 + in * 16 + l15;
      float bval = bias[col];
      #pragma unroll
      for (int r = 0; r < 4; ++r) {
        int row = m0 + wm * 64 + im * 16 + l4 * 4 + r;
        out[(size_t)row * DM + col] = acc[im][in][r] + bval;
      }
    }
}

// ---------------------------------------------------------------- launch
extern "C" void kernel_launch(void* const* d_in, const int* in_sizes, int n_in,
                              void* d_out, int out_size, void* d_ws, size_t ws_size,
                              hipStream_t stream) {
  (void)in_sizes; (void)n_in; (void)out_size; (void)ws_size;
  const float* x  = (const float*)d_in[0];
  const float* wq = (const float*)d_in[1];
  const float* bq = (const float*)d_in[2];
  const float* wp = (const float*)d_in[3];
  const float* bp = (const float*)d_in[4];
  float* out  = (float*)d_out;
  float* attn = out + (size_t)SEQ * DM;

  char* ws = (char*)d_ws;
  bf16* xb    = (bf16*)(ws + (size_t) 0);          // 4 MB  x bf16            [dead after qkv gemm]
  bf16* wqb   = (bf16*)(ws + ((size_t)4  << 20));  // 6 MB  w_qkv bf16        [dead after qkv gemm]
  bf16* wpb   = (bf16*)(ws + ((size_t)10 << 20));  // 2 MB  w_proj bf16
  bf16* qarr  = (bf16*)(ws + ((size_t)12 << 20));  // 4 MB  q [h][i][d] (scale*log2e folded)
  bf16* karr  = (bf16*)(ws + ((size_t)16 << 20));  // 4 MB  k [h][j][d]
  bf16* vt    = (bf16*)(ws + ((size_t)24 << 20));  // 4 MB  vT [h][d][j] (written by qkv epilogue)
  bf16* ao    = (bf16*)(ws + ((size_t)28 << 20));  // 4 MB  attn-out rows [i][h*64+d]
  float* aof  = (float*)(ws + (size_t)0);          // 8 MB  f32 O accum (overlays xb+wqb, dead by then)
  float* psums= (float*)(ws + ((size_t)8 << 20));  // 512KB partial sums (overlays wqb tail, dead by then)

  k_cvt<<<dim3(1024), dim3(256), 0, stream>>>(x, wq, wp, xb, wqb, wpb);
  k_gemm_qkv<<<dim3(16, 24), dim3(256), 0, stream>>>(xb, wqb, bq, qarr, karr, vt);
  k_attn1<<<dim3(1024), dim3(256), 0, stream>>>(qarr, karr, psums, aof);
  k_attn2<<<dim3(1024), dim3(256), 0, stream>>>(qarr, karr, vt, psums, attn, aof);
  k_ored<<<dim3(NH * SEQ * HD / 4 / 256), dim3(256), 0, stream>>>(aof, ao);
  k_gemm_proj<<<dim3(16, 8), dim3(256), 0, stream>>>(ao, wpb, bp, out);
}